// Round 16
// baseline (499.068 us; speedup 1.0000x reference)
//
#include <hip/hip_runtime.h>
#include <stdint.h>

typedef unsigned short u16;
typedef __attribute__((ext_vector_type(8))) short short8;
typedef __attribute__((ext_vector_type(4))) float f32x4;

#define SWZ(r) (((r) & 7) << 4)
#define SWZV(dr) ((((dr) & 7) ^ (((dr) >> 3) & 7)) << 4)
#define SCALE 0.125f

__device__ __forceinline__ u16 f2bf(float f) {
  unsigned int x = __float_as_uint(f);
  x += 0x7fffu + ((x >> 16) & 1u);
  return (u16)(x >> 16);
}

// packed f32x2 -> bf16x2 (RNE)
__device__ __forceinline__ unsigned int cvtpk_bf16(float lo, float hi) {
  unsigned int r;
  asm("v_cvt_pk_bf16_f32 %0, %1, %2" : "=v"(r) : "v"(lo), "v"(hi));
  return r;
}

__device__ __forceinline__ f32x4 mfma16(short8 a, short8 b, f32x4 c) {
  return __builtin_amdgcn_mfma_f32_16x16x32_bf16(a, b, c, 0, 0, 0);
}

__device__ __forceinline__ void gload_lds16(const u16* g, u16* l) {
  __builtin_amdgcn_global_load_lds(
      (const __attribute__((address_space(1))) unsigned int*)g,
      (__attribute__((address_space(3))) unsigned int*)l, 16, 0, 0);
}

// XCD-chunked bijective swizzle (nwg % 8 == 0 by construction here)
__device__ __forceinline__ int xcd_swz(int bid, int nwg) {
  int cpx = nwg >> 3;
  return (bid & 7) * cpx + (bid >> 3);
}

// NT loads: f32 sources are read-once (neutral-verified r14)
__device__ __forceinline__ void cvt8(const float* src, u16* dst) {
  f32x4 a = __builtin_nontemporal_load((const f32x4*)src);
  f32x4 b = __builtin_nontemporal_load((const f32x4*)(src + 4));
  uint4 u;
  u.x = cvtpk_bf16(a[0], a[1]);
  u.y = cvtpk_bf16(a[2], a[3]);
  u.z = cvtpk_bf16(b[0], b[1]);
  u.w = cvtpk_bf16(b[2], b[3]);
  *(uint4*)dst = u;
}

// ---------------- merged conversion: 4 weights + ent + feat, grid-stride --------
__global__ __launch_bounds__(256) void cvt_all_kernel(
    const float* __restrict__ w0, const float* __restrict__ w1,
    const float* __restrict__ w2, const float* __restrict__ w3,
    const float* __restrict__ ent, const float* __restrict__ feat,
    u16* __restrict__ Wbf, u16* __restrict__ entbf, u16* __restrict__ featbf,
    int nE8, int nF8) {
  const int nW8 = 524288;
  int total = nW8 + nE8 + nF8;
  int i = blockIdx.x * 256 + threadIdx.x;
  int stride = gridDim.x * 256;
  for (; i < total; i += stride) {
    if (i < nW8) {
      int mi = i >> 17;
      const float* s = (mi == 0) ? w0 : (mi == 1) ? w1 : (mi == 2) ? w2 : w3;
      size_t off = (size_t)(i & 131071) * 8;
      cvt8(s + off, Wbf + (size_t)mi * 1048576 + off);
    } else if (i < nW8 + nE8) {
      size_t off = (size_t)(i - nW8) * 8;
      cvt8(ent + off, entbf + off);
    } else {
      size_t off = (size_t)(i - nW8 - nE8) * 8;
      cvt8(feat + off, featbf + off);
    }
  }
}

__global__ __launch_bounds__(256) void cvt_a_kernel(
    const float* __restrict__ src, u16* __restrict__ dst, int n8) {
  int i = blockIdx.x * 256 + threadIdx.x;
  int stride = gridDim.x * 256;
  for (; i < n8; i += stride) cvt8(src + (size_t)i * 8, dst + (size_t)i * 8);
}

// ---------------- GEMM core: C[r,o]=sum A[r,:]W[o,:]+b  (HW-validated) ---------
template <bool OUT_F32>
__device__ __forceinline__ void gemm_core(
    const u16* __restrict__ A, const u16* __restrict__ B,
    const float* __restrict__ bias0, const float* __restrict__ bias1,
    void* __restrict__ Cv, int ldc, int bx, int by, u16* As, u16* Bs) {
  const int tid = threadIdx.x;
  const int lane = tid & 63;
  const int w = tid >> 6;
  const int wr = w >> 1, wc = w & 1;
  const int l15 = lane & 15, lg = lane >> 4;
  const int brow = by * 128;
  const int bcol = bx * 128;

  f32x4 acc[4][4] = {};

  for (int k0 = 0; k0 < 1024; k0 += 64) {
#pragma unroll
    for (int p = 0; p < 4; ++p) {
      int flat = p * 256 + tid;
      int row = flat >> 3;
      int scb = ((flat & 7) * 16) ^ SWZ(row);
      gload_lds16(B + (size_t)(bcol + row) * 1024 + k0 + (scb >> 1),
                  Bs + (size_t)flat * 8);
    }
#pragma unroll
    for (int p = 0; p < 4; ++p) {
      int flat = p * 256 + tid;
      int row = flat >> 3;
      int scb = ((flat & 7) * 16) ^ SWZ(row);
      gload_lds16(A + (size_t)(brow + row) * 1024 + k0 + (scb >> 1),
                  As + (size_t)flat * 8);
    }
    __syncthreads();

    short8 af[4][2], bfr[4][2];
#pragma unroll
    for (int i = 0; i < 4; ++i) {
#pragma unroll
      for (int kk = 0; kk < 2; ++kk) {
        int ar = wr * 64 + i * 16 + l15;
        af[i][kk] = *(const short8*)((const char*)As + ar * 128 +
                                     ((kk * 64 + lg * 16) ^ SWZ(ar)));
        int br = wc * 64 + i * 16 + l15;
        bfr[i][kk] = *(const short8*)((const char*)Bs + br * 128 +
                                      ((kk * 64 + lg * 16) ^ SWZ(br)));
      }
    }
#pragma unroll
    for (int i = 0; i < 4; ++i)
#pragma unroll
      for (int j = 0; j < 4; ++j)
#pragma unroll
        for (int kk = 0; kk < 2; ++kk)
          acc[i][j] = mfma16(af[i][kk], bfr[j][kk], acc[i][j]);
    __syncthreads();
  }

#pragma unroll
  for (int j = 0; j < 4; ++j) {
    int col = bcol + wc * 64 + j * 16 + l15;
    const float* bp = (col < 1024) ? bias0 : bias1;
    float bv = bp[col & 1023];
#pragma unroll
    for (int i = 0; i < 4; ++i) {
      int row0 = brow + wr * 64 + i * 16 + lg * 4;
#pragma unroll
      for (int r = 0; r < 4; ++r) {
        float v = acc[i][j][r] + bv;
        if constexpr (OUT_F32)
          ((float*)Cv)[(size_t)(row0 + r) * ldc + col] = v;
        else
          ((u16*)Cv)[(size_t)(row0 + r) * ldc + col] = f2bf(v);
      }
    }
  }
}

// ---------------- combined Q + KV projection per modality (932 TF proven) ------
__global__ __launch_bounds__(256, 2) void qkv_gemm_kernel(
    const u16* __restrict__ A0, const u16* __restrict__ B0,
    const float* __restrict__ bq, u16* __restrict__ C0, int gx0, int nwg0,
    const u16* __restrict__ A1, const u16* __restrict__ B1,
    const float* __restrict__ bk, const float* __restrict__ bv,
    u16* __restrict__ C1, int gx1, int nwg1) {
  __shared__ __attribute__((aligned(16))) u16 As[128 * 64];
  __shared__ __attribute__((aligned(16))) u16 Bs[128 * 64];
  int bid = blockIdx.x;
  if (bid < nwg0) {
    int lid = xcd_swz(bid, nwg0);
    gemm_core<false>(A0, B0, bq, bq, C0, 1024, lid % gx0, lid / gx0, As, Bs);
  } else {
    int lid = xcd_swz(bid - nwg0, nwg1);
    gemm_core<false>(A1, B1, bk, bv, C1, 2048, lid % gx1, lid / gx1, As, Bs);
  }
}

// ---------------- 2-segment Wo GEMM (f32 out; 512 blocks = full 2/CU) ----------
__global__ __launch_bounds__(256, 2) void wo2_kernel(
    const u16* __restrict__ A0, const u16* __restrict__ B0,
    const float* __restrict__ b0, float* __restrict__ C0, int n0,
    const u16* __restrict__ A1, const u16* __restrict__ B1,
    const float* __restrict__ b1, float* __restrict__ C1) {
  __shared__ __attribute__((aligned(16))) u16 As[128 * 64];
  __shared__ __attribute__((aligned(16))) u16 Bs[128 * 64];
  int bid = blockIdx.x;
  if (bid < n0) {
    int lid = xcd_swz(bid, n0);
    gemm_core<true>(A0, B0, b0, b0, C0, 1024, lid % 8, lid / 8, As, Bs);
  } else {
    int lid = xcd_swz(bid - n0, gridDim.x - n0);
    gemm_core<true>(A1, B1, b1, b1, C1, 1024, lid % 8, lid / 8, As, Bs);
  }
}

// ---------------- GEMM (legacy template for fallback paths) ----------
template <bool A_F32, bool OUT_F32>
__global__ __launch_bounds__(256, 2) void gemm_bias_kernel(
    const void* __restrict__ Av, const u16* __restrict__ B,
    const float* __restrict__ bias0, const float* __restrict__ bias1,
    void* __restrict__ Cv, int ldc) {
  __shared__ __attribute__((aligned(16))) u16 As[128 * 64];
  __shared__ __attribute__((aligned(16))) u16 Bs[128 * 64];
  const int tid = threadIdx.x;
  const int nwg = gridDim.x * gridDim.y;
  const int lid = xcd_swz(blockIdx.y * gridDim.x + blockIdx.x, nwg);
  const int bx = lid % gridDim.x;
  const int by = lid / gridDim.x;

  if constexpr (!A_F32) {
    gemm_core<OUT_F32>((const u16*)Av, B, bias0, bias1, Cv, ldc, bx, by, As, Bs);
    return;
  } else {
    const int lane = tid & 63;
    const int w = tid >> 6;
    const int wr = w >> 1, wc = w & 1;
    const int l15 = lane & 15, lg = lane >> 4;
    const int brow = by * 128;
    const int bcol = bx * 128;
    f32x4 acc[4][4] = {};
    for (int k0 = 0; k0 < 1024; k0 += 64) {
#pragma unroll
      for (int p = 0; p < 4; ++p) {
        int flat = p * 256 + tid;
        int row = flat >> 3;
        int scb = ((flat & 7) * 16) ^ SWZ(row);
        gload_lds16(B + (size_t)(bcol + row) * 1024 + k0 + (scb >> 1),
                    Bs + (size_t)flat * 8);
      }
      const float* Af = (const float*)Av;
#pragma unroll
      for (int p = 0; p < 4; ++p) {
        int flat = p * 256 + tid;
        int row = flat >> 3;
        int c8 = flat & 7;
        const float* src = Af + (size_t)(brow + row) * 1024 + k0 + c8 * 8;
        float4 v0 = ((const float4*)src)[0];
        float4 v1 = ((const float4*)src)[1];
        uint4 u;
        u.x = cvtpk_bf16(v0.x, v0.y);
        u.y = cvtpk_bf16(v0.z, v0.w);
        u.z = cvtpk_bf16(v1.x, v1.y);
        u.w = cvtpk_bf16(v1.z, v1.w);
        *(uint4*)((char*)As + row * 128 + ((c8 * 16) ^ SWZ(row))) = u;
      }
      __syncthreads();
      short8 af[4][2], bfr[4][2];
#pragma unroll
      for (int i = 0; i < 4; ++i) {
#pragma unroll
        for (int kk = 0; kk < 2; ++kk) {
          int ar = wr * 64 + i * 16 + l15;
          af[i][kk] = *(const short8*)((const char*)As + ar * 128 +
                                       ((kk * 64 + lg * 16) ^ SWZ(ar)));
          int br = wc * 64 + i * 16 + l15;
          bfr[i][kk] = *(const short8*)((const char*)Bs + br * 128 +
                                        ((kk * 64 + lg * 16) ^ SWZ(br)));
        }
      }
#pragma unroll
      for (int i = 0; i < 4; ++i)
#pragma unroll
        for (int j = 0; j < 4; ++j)
#pragma unroll
          for (int kk = 0; kk < 2; ++kk)
            acc[i][j] = mfma16(af[i][kk], bfr[j][kk], acc[i][j]);
      __syncthreads();
    }
#pragma unroll
    for (int j = 0; j < 4; ++j) {
      int col = bcol + wc * 64 + j * 16 + l15;
      const float* bp = (col < 1024) ? bias0 : bias1;
      float bv = bp[col & 1023];
#pragma unroll
      for (int i = 0; i < 4; ++i) {
        int row0 = brow + wr * 64 + i * 16 + lg * 4;
#pragma unroll
        for (int r = 0; r < 4; ++r) {
          float v = acc[i][j][r] + bv;
          if constexpr (OUT_F32)
            ((float*)Cv)[(size_t)(row0 + r) * ldc + col] = v;
          else
            ((u16*)Cv)[(size_t)(row0 + r) * ldc + col] = f2bf(v);
        }
      }
    }
  }
}

// ---------------- MFMA flash attention core (r11 proven) ----------------
__device__ __forceinline__ void attn_core(
    const u16* __restrict__ Q, const u16* __restrict__ KV,
    const int* __restrict__ mask, u16* __restrict__ AO, int S, int mbase,
    int lid) {
  __shared__ __attribute__((aligned(16))) u16 Ks[64 * 64];
  __shared__ __attribute__((aligned(16))) u16 Vt[64 * 64];
  __shared__ __attribute__((aligned(16))) u16 Ps[4 * 32 * 64];
  __shared__ float mb[64];

  const int tid = threadIdx.x;
  const int lane = tid & 63;
  const int w = tid >> 6;
  const int ml = lid >> 4;
  const int h = lid & 15;
  const int mg = mbase + ml;
  const int l15 = lane & 15, lg = lane >> 4;

  short8 qf[2][2];
#pragma unroll
  for (int qb = 0; qb < 2; ++qb)
#pragma unroll
    for (int kk = 0; kk < 2; ++kk)
      qf[qb][kk] = *(const short8*)(Q + (size_t)(mg * 128 + w * 32 + qb * 16 + l15) * 1024 +
                                    h * 64 + kk * 32 + lg * 8);

  float mrun[2][4], lrun[2][4];
  f32x4 oacc[2][4] = {};
#pragma unroll
  for (int qb = 0; qb < 2; ++qb)
#pragma unroll
    for (int r = 0; r < 4; ++r) {
      mrun[qb][r] = -1e30f;
      lrun[qb][r] = 0.0f;
    }

  const size_t kvbase = (size_t)ml * S * 2048 + h * 64;

  for (int st = 0; st < S; st += 64) {
    if (tid < 64)
      mb[tid] = (mask[(size_t)mg * S + st + tid] > 0) ? 0.0f : -1e30f;
#pragma unroll
    for (int p = 0; p < 2; ++p) {
      int flat = p * 256 + tid;
      int row = flat >> 3;
      int c = flat & 7;
      short8 v = *(const short8*)(KV + kvbase + (size_t)(st + row) * 2048 + c * 8);
      *(short8*)((char*)Ks + row * 128 + ((c * 16) ^ SWZ(row))) = v;
    }
    {
      int sp = (tid >> 3) * 2;
      int c = tid & 7;
      const u16* src = KV + kvbase + 1024 + (size_t)(st + sp) * 2048 + c * 8;
      short8 v0 = *(const short8*)(src);
      short8 v1 = *(const short8*)(src + 2048);
#pragma unroll
      for (int j = 0; j < 8; ++j) {
        int dr = c * 8 + j;
        unsigned int val = (unsigned int)(u16)v0[j] | ((unsigned int)(u16)v1[j] << 16);
        *(unsigned int*)((char*)Vt + dr * 128 + ((sp * 2) ^ SWZV(dr))) = val;
      }
    }
    __syncthreads();

    short8 kf[4][2];
#pragma unroll
    for (int sb = 0; sb < 4; ++sb)
#pragma unroll
      for (int kk = 0; kk < 2; ++kk) {
        int row = sb * 16 + l15;
        kf[sb][kk] = *(const short8*)((const char*)Ks + row * 128 +
                                      ((kk * 64 + lg * 16) ^ SWZ(row)));
      }
    f32x4 sc[2][4] = {};
#pragma unroll
    for (int qb = 0; qb < 2; ++qb)
#pragma unroll
      for (int sb = 0; sb < 4; ++sb)
#pragma unroll
        for (int kk = 0; kk < 2; ++kk)
          sc[qb][sb] = mfma16(qf[qb][kk], kf[sb][kk], sc[qb][sb]);

    float mbv[4];
#pragma unroll
    for (int sb = 0; sb < 4; ++sb) mbv[sb] = mb[sb * 16 + l15];

#pragma unroll
    for (int qb = 0; qb < 2; ++qb) {
#pragma unroll
      for (int r = 0; r < 4; ++r) {
        float s0 = sc[qb][0][r] * SCALE + mbv[0];
        float s1 = sc[qb][1][r] * SCALE + mbv[1];
        float s2 = sc[qb][2][r] * SCALE + mbv[2];
        float s3 = sc[qb][3][r] * SCALE + mbv[3];
        float t = fmaxf(fmaxf(s0, s1), fmaxf(s2, s3));
        for (int d = 1; d < 16; d <<= 1) t = fmaxf(t, __shfl_xor(t, d));
        float mnew = fmaxf(mrun[qb][r], t);
        float resc = __expf(mrun[qb][r] - mnew);
        float p0 = __expf(s0 - mnew);
        float p1 = __expf(s1 - mnew);
        float p2 = __expf(s2 - mnew);
        float p3 = __expf(s3 - mnew);
        float rs = p0 + p1 + p2 + p3;
        for (int d = 1; d < 16; d <<= 1) rs += __shfl_xor(rs, d);
        lrun[qb][r] = lrun[qb][r] * resc + rs;
        mrun[qb][r] = mnew;
#pragma unroll
        for (int db = 0; db < 4; ++db) oacc[qb][db][r] *= resc;
        int row = qb * 16 + lg * 4 + r;
        char* pbase = (char*)Ps + (w * 32 + row) * 128;
        int colb = 2 * l15;
        *(u16*)(pbase + ((0 * 32 + colb) ^ SWZ(row))) = f2bf(p0);
        *(u16*)(pbase + ((1 * 32 + colb) ^ SWZ(row))) = f2bf(p1);
        *(u16*)(pbase + ((2 * 32 + colb) ^ SWZ(row))) = f2bf(p2);
        *(u16*)(pbase + ((3 * 32 + colb) ^ SWZ(row))) = f2bf(p3);
      }
    }
    asm volatile("" ::: "memory");  // Ps wave-private: compiler fence only

    short8 pf[2][2], vf[4][2];
#pragma unroll
    for (int qb = 0; qb < 2; ++qb)
#pragma unroll
      for (int kk = 0; kk < 2; ++kk) {
        int row = qb * 16 + l15;
        pf[qb][kk] = *(const short8*)((const char*)Ps + (w * 32 + row) * 128 +
                                      ((kk * 64 + lg * 16) ^ SWZ(row)));
      }
#pragma unroll
    for (int db = 0; db < 4; ++db)
#pragma unroll
      for (int kk = 0; kk < 2; ++kk) {
        int row = db * 16 + l15;
        vf[db][kk] = *(const short8*)((const char*)Vt + row * 128 +
                                      ((kk * 64 + lg * 16) ^ SWZV(row)));
      }
#pragma unroll
    for (int qb = 0; qb < 2; ++qb)
#pragma unroll
      for (int db = 0; db < 4; ++db)
#pragma unroll
        for (int kk = 0; kk < 2; ++kk)
          oacc[qb][db] = mfma16(pf[qb][kk], vf[db][kk], oacc[qb][db]);
    __syncthreads();
  }

#pragma unroll
  for (int qb = 0; qb < 2; ++qb)
#pragma unroll
    for (int db = 0; db < 4; ++db)
#pragma unroll
      for (int r = 0; r < 4; ++r) {
        int grow = mg * 128 + w * 32 + qb * 16 + lg * 4 + r;
        int gcol = h * 64 + db * 16 + l15;
        float v = oacc[qb][db][r] / lrun[qb][r];
        AO[(size_t)grow * 1024 + gcol] = f2bf(v);
      }
}

__global__ __launch_bounds__(256, 2) void attn_mfma_kernel(
    const u16* __restrict__ Q, const u16* __restrict__ KV,
    const int* __restrict__ mask, u16* __restrict__ AO, int S, int mbase) {
  int lid = xcd_swz(blockIdx.x, gridDim.x);
  attn_core(Q, KV, mask, AO, S, mbase, lid);
}

// 2-segment attention: text (512 blocks) | image (512 blocks) — r12-proven
__global__ __launch_bounds__(256, 2) void attn2_kernel(
    const u16* __restrict__ Q0, const u16* __restrict__ KV0,
    const int* __restrict__ m0, u16* __restrict__ AO0, int S0,
    const u16* __restrict__ Q1, const u16* __restrict__ KV1,
    const int* __restrict__ m1, u16* __restrict__ AO1, int S1) {
  int bid = blockIdx.x;
  if (bid < 512) {
    attn_core(Q0, KV0, m0, AO0, S0, 0, xcd_swz(bid, 512));
  } else {
    attn_core(Q1, KV1, m1, AO1, S1, 0, xcd_swz(bid - 512, 512));
  }
}

// ---------------- residual + LayerNorm ----------------
__device__ __forceinline__ void ln_core(
    const float* __restrict__ X, const float* __restrict__ O,
    const float* __restrict__ g, const float* __restrict__ b,
    float* __restrict__ out, int row) {
  int tid = threadIdx.x;
  const float* xr = X + (size_t)row * 1024;
  const float* orr = O + (size_t)row * 1024;
  float4 xv = *(const float4*)(xr + tid * 4);
  float4 ov = *(const float4*)(orr + tid * 4);
  float v0 = xv.x + ov.x, v1 = xv.y + ov.y, v2 = xv.z + ov.z, v3 = xv.w + ov.w;
  float s = v0 + v1 + v2 + v3;
  float s2 = v0 * v0 + v1 * v1 + v2 * v2 + v3 * v3;
  for (int d = 1; d < 64; d <<= 1) {
    s += __shfl_xor(s, d);
    s2 += __shfl_xor(s2, d);
  }
  __shared__ float ps[4], ps2[4];
  int w = tid >> 6;
  if ((tid & 63) == 0) {
    ps[w] = s;
    ps2[w] = s2;
  }
  __syncthreads();
  s = ps[0] + ps[1] + ps[2] + ps[3];
  s2 = ps2[0] + ps2[1] + ps2[2] + ps2[3];
  float mu = s * (1.0f / 1024.0f);
  float var = s2 * (1.0f / 1024.0f) - mu * mu;
  float rstd = rsqrtf(var + 1e-5f);
  float4 gv = *(const float4*)(g + tid * 4);
  float4 bv = *(const float4*)(b + tid * 4);
  float4 ou;
  ou.x = (v0 - mu) * rstd * gv.x + bv.x;
  ou.y = (v1 - mu) * rstd * gv.y + bv.y;
  ou.z = (v2 - mu) * rstd * gv.z + bv.z;
  ou.w = (v3 - mu) * rstd * gv.w + bv.w;
  *(float4*)(out + (size_t)row * 1024 + tid * 4) = ou;
}

__global__ __launch_bounds__(256) void ln_kernel(
    const float* __restrict__ X, const float* __restrict__ O,
    const float* __restrict__ g, const float* __restrict__ b,
    float* __restrict__ out) {
  ln_core(X, O, g, b, out, blockIdx.x);
}

__global__ __launch_bounds__(256) void ln2_kernel(
    const float* __restrict__ X0, const float* __restrict__ O0,
    const float* __restrict__ g0, const float* __restrict__ b0,
    const float* __restrict__ X1, const float* __restrict__ O1,
    const float* __restrict__ g1, const float* __restrict__ b1,
    float* __restrict__ out) {
  int row = blockIdx.x;
  if (row < 4096)
    ln_core(X0, O0, g0, b0, out, row);
  else
    ln_core(X1, O1, g1, b1, out + 4194304, row - 4096);
}

extern "C" void kernel_launch(void* const* d_in, const int* in_sizes, int n_in,
                              void* d_out, int out_size, void* d_ws, size_t ws_size,
                              hipStream_t stream) {
  const float* ent_t = (const float*)d_in[0];
  const float* ent_i = (const float*)d_in[1];
  const float* img_feat = (const float*)d_in[2];
  const float* txt_feat = (const float*)d_in[3];
  const int* img_mask = (const int*)d_in[4];
  const int* txt_mask = (const int*)d_in[5];
  const float* W[8];
  const float* Bv[8];
  for (int i = 0; i < 8; ++i) {
    W[i] = (const float*)d_in[6 + 2 * i];
    Bv[i] = (const float*)d_in[7 + 2 * i];
  }
  const float* g_t = (const float*)d_in[22];
  const float* beta_t = (const float*)d_in[23];
  const float* g_i = (const float*)d_in[24];
  const float* beta_i = (const float*)d_in[25];
  float* out = (float*)d_out;
  char* ws = (char*)d_ws;

  if (ws_size >= (400ull << 20)) {
    // ===== r16 path: per-modality cvt→qkv (proven adjacency), merged
    //       attn2 + wo2 + ln2 tail. 7 dispatches. 344 MiB. =====
    // Wbf 16M | Qbf_t 8M | Qbf_i 8M | AObf_t 8M | AObf_i 8M | entbf 8M
    // | KVt 128M (Of32_t/Of32_i alias) | KVi 96M | featbf 64M
    u16* Wbf = (u16*)ws;
    u16* Qbf_t = (u16*)(ws + (16ull << 20));
    u16* Qbf_i = (u16*)(ws + (24ull << 20));
    u16* AObf_t = (u16*)(ws + (32ull << 20));
    u16* AObf_i = (u16*)(ws + (40ull << 20));
    u16* entbf = (u16*)(ws + (48ull << 20));
    u16* KVt = (u16*)(ws + (56ull << 20));
    u16* KVi = (u16*)(ws + (184ull << 20));
    u16* featbf = (u16*)(ws + (280ull << 20));
    float* Of32_t = (float*)(ws + (56ull << 20));            // alias KVt
    float* Of32_i = (float*)(ws + (72ull << 20));            // alias KVt

    for (int mod = 0; mod < 2; ++mod) {
      const float* ent = mod ? ent_i : ent_t;
      const float* feat = mod ? img_feat : txt_feat;
      u16* Qbf = mod ? Qbf_i : Qbf_t;
      u16* KVc = mod ? KVi : KVt;
      int S = mod ? 768 : 1024;
      int crows = 32 * S;

      const u16* wq = Wbf + (size_t)mod * 4 * 1048576;
      const u16* wkv = Wbf + ((size_t)mod * 4 + 1) * 1048576;

      cvt_all_kernel<<<2048, 256, 0, stream>>>(
          W[mod * 4 + 0], W[mod * 4 + 1], W[mod * 4 + 2], W[mod * 4 + 3],
          ent, feat, Wbf + (size_t)mod * 4 * 1048576, entbf, featbf,
          4096 * 128, crows * 128);

      qkv_gemm_kernel<<<256 + 16 * (crows / 128), 256, 0, stream>>>(
          entbf, wq, Bv[mod * 4 + 0], Qbf, 8, 256,
          featbf, wkv, Bv[mod * 4 + 1], Bv[mod * 4 + 2], KVc, 16,
          16 * (crows / 128));
    }

    attn2_kernel<<<1024, 256, 0, stream>>>(
        Qbf_t, KVt, txt_mask, AObf_t, 1024,
        Qbf_i, KVi, img_mask, AObf_i, 768);

    wo2_kernel<<<512, 256, 0, stream>>>(
        AObf_t, Wbf + 3ull * 1048576, Bv[3], Of32_t, 256,
        AObf_i, Wbf + 7ull * 1048576, Bv[7], Of32_i);

    ln2_kernel<<<8192, 256, 0, stream>>>(
        ent_t, Of32_t, g_t, beta_t,
        ent_i, Of32_i, g_i, beta_i, out);
    return;
  }

  if (ws_size >= (240ull << 20)) {
    // ===== r15 path (proven 493 µs): per-modality cvt→qkv→attn,
    //       deferred merged wo2 + ln2. 8 dispatches. =====
    u16* Wbf = (u16*)ws;
    u16* Qbf = (u16*)(ws + (16ull << 20));
    u16* AObf_t = (u16*)(ws + (24ull << 20));
    u16* AObf_i = (u16*)(ws + (32ull << 20));
    u16* entbf = (u16*)(ws + (40ull << 20));
    u16* KVc = (u16*)(ws + (48ull << 20));
    u16* featbf = (u16*)(ws + (176ull << 20));
    float* Of32_t = (float*)(ws + (48ull << 20));
    float* Of32_i = (float*)(ws + (48ull << 20) + (16ull << 20));

    for (int mod = 0; mod < 2; ++mod) {
      const float* ent = mod ? ent_i : ent_t;
      const float* feat = mod ? img_feat : txt_feat;
      const int* msk = mod ? img_mask : txt_mask;
      u16* AObf = mod ? AObf_i : AObf_t;
      int S = mod ? 768 : 1024;
      int crows = 32 * S;

      const u16* wq = Wbf + (size_t)mod * 4 * 1048576;
      const u16* wkv = Wbf + ((size_t)mod * 4 + 1) * 1048576;

      cvt_all_kernel<<<2048, 256, 0, stream>>>(
          W[mod * 4 + 0], W[mod * 4 + 1], W[mod * 4 + 2], W[mod * 4 + 3],
          ent, feat, Wbf + (size_t)mod * 4 * 1048576, entbf, featbf,
          4096 * 128, crows * 128);

      qkv_gemm_kernel<<<256 + 16 * (crows / 128), 256, 0, stream>>>(
          entbf, wq, Bv[mod * 4 + 0], Qbf, 8, 256,
          featbf, wkv, Bv[mod * 4 + 1], Bv[mod * 4 + 2], KVc, 16,
          16 * (crows / 128));

      attn_mfma_kernel<<<512, 256, 0, stream>>>(Qbf, KVc, msk, AObf, S, 0);
    }

    wo2_kernel<<<512, 256, 0, stream>>>(
        AObf_t, Wbf + 3ull * 1048576, Bv[3], Of32_t, 256,
        AObf_i, Wbf + 7ull * 1048576, Bv[7], Of32_i);

    ln2_kernel<<<8192, 256, 0, stream>>>(
        ent_t, Of32_t, g_t, beta_t,
        ent_i, Of32_i, g_i, beta_i, out);
    return;
  }

  // ============ fallback: r11 proven path ============
  int nc = 0;
  size_t Xt = 0;
  for (int t = 1; t <= 4; t <<= 1) {
    size_t x = 134217728ull / t;
    if ((32ull << 20) + x + x / 2 <= ws_size) { nc = t; Xt = x; break; }
  }

  u16* Wbf = (u16*)ws;
  u16* Qbf = (u16*)(ws + (8ull << 20));
  u16* AObf = (u16*)(ws + (16ull << 20));

  if (nc > 0) {
    u16* entbf = (u16*)(ws + (24ull << 20));
    u16* KVc = (u16*)(ws + (32ull << 20));
    u16* featbf = (u16*)(ws + (32ull << 20) + Xt);
    float* Of32 = (float*)(ws + (32ull << 20));
    const int mpc = 32 / nc;

    for (int mod = 0; mod < 2; ++mod) {
      const float* ent = mod ? ent_i : ent_t;
      const float* feat = mod ? img_feat : txt_feat;
      const int* msk = mod ? img_mask : txt_mask;
      int S = mod ? 768 : 1024;
      int crows = mpc * S;

      const u16* wq = Wbf;
      const u16* wkv = Wbf + 1ull * 1048576;
      const u16* wo = Wbf + 3ull * 1048576;

      cvt_all_kernel<<<2048, 256, 0, stream>>>(
          W[mod * 4 + 0], W[mod * 4 + 1], W[mod * 4 + 2], W[mod * 4 + 3],
          ent, feat, Wbf, entbf, featbf, 4096 * 128, crows * 128);

      for (int c = 0; c < nc; ++c) {
        if (c > 0) {
          const float* featc = feat + (size_t)c * mpc * S * 1024;
          cvt_a_kernel<<<2048, 256, 0, stream>>>(featc, featbf, crows * 128);
        }
        int nwg0 = (c == 0) ? 256 : 0;
        int nwg1 = 16 * (crows / 128);
        qkv_gemm_kernel<<<nwg0 + nwg1, 256, 0, stream>>>(
            entbf, wq, Bv[mod * 4 + 0], Qbf, 8, nwg0,
            featbf, wkv, Bv[mod * 4 + 1], Bv[mod * 4 + 2], KVc, 16, nwg1);
        attn_mfma_kernel<<<mpc * 16, 256, 0, stream>>>(Qbf, KVc, msk, AObf, S, c * mpc);
      }

      gemm_bias_kernel<false, true><<<dim3(8, 32), 256, 0, stream>>>(
          AObf, wo, Bv[mod * 4 + 3], Bv[mod * 4 + 3], Of32, 1024);
      ln_kernel<<<4096, 256, 0, stream>>>(ent, Of32,
                                          mod ? g_i : g_t, mod ? beta_i : beta_t,
                                          out + (size_t)mod * 4194304);
    }
  } else {
    int ncf = 4;
    if (ws_size >= (152ull << 20)) ncf = 1;
    else if (ws_size >= (88ull << 20)) ncf = 2;
    u16* KVc = (u16*)(ws + (24ull << 20));
    float* Of32 = (float*)(ws + (24ull << 20));
    const int mpc = 32 / ncf;

    for (int mod = 0; mod < 2; ++mod) {
      const float* ent = mod ? ent_i : ent_t;
      const float* feat = mod ? img_feat : txt_feat;
      const int* msk = mod ? img_mask : txt_mask;
      int S = mod ? 768 : 1024;

      cvt_all_kernel<<<2048, 256, 0, stream>>>(
          W[mod * 4 + 0], W[mod * 4 + 1], W[mod * 4 + 2], W[mod * 4 + 3],
          ent, ent, Wbf, Qbf, Qbf, 0, 0);

      const u16* wq = Wbf;
      const u16* wkv = Wbf + 1ull * 1048576;
      const u16* wo = Wbf + 3ull * 1048576;

      gemm_bias_kernel<true, false><<<dim3(8, 32), 256, 0, stream>>>(
          ent, wq, Bv[mod * 4 + 0], Bv[mod * 4 + 0], Qbf, 1024);

      int crows = mpc * S;
      for (int c = 0; c < ncf; ++c) {
        const float* featc = feat + (size_t)c * mpc * S * 1024;
        gemm_bias_kernel<true, false><<<dim3(16, crows / 128), 256, 0, stream>>>(
            featc, wkv, Bv[mod * 4 + 1], Bv[mod * 4 + 2], KVc, 2048);
        attn_mfma_kernel<<<mpc * 16, 256, 0, stream>>>(Qbf, KVc, msk, AObf, S, c * mpc);
      }

      gemm_bias_kernel<false, true><<<dim3(8, 32), 256, 0, stream>>>(
          AObf, wo, Bv[mod * 4 + 3], Bv[mod * 4 + 3], Of32, 1024);
      ln_kernel<<<4096, 256, 0, stream>>>(ent, Of32,
                                          mod ? g_i : g_t, mod ? beta_i : beta_t,
                                          out + (size_t)mod * 4194304);
    }
  }
}

// Round 17
// 492.873 us; speedup vs baseline: 1.0126x; 1.0126x over previous
//
#include <hip/hip_runtime.h>
#include <stdint.h>

typedef unsigned short u16;
typedef __attribute__((ext_vector_type(8))) short short8;
typedef __attribute__((ext_vector_type(4))) float f32x4;

#define SWZ(r) (((r) & 7) << 4)
#define SWZV(dr) ((((dr) & 7) ^ (((dr) >> 3) & 7)) << 4)
#define SCALE 0.125f

__device__ __forceinline__ u16 f2bf(float f) {
  unsigned int x = __float_as_uint(f);
  x += 0x7fffu + ((x >> 16) & 1u);
  return (u16)(x >> 16);
}

// packed f32x2 -> bf16x2 (RNE)
__device__ __forceinline__ unsigned int cvtpk_bf16(float lo, float hi) {
  unsigned int r;
  asm("v_cvt_pk_bf16_f32 %0, %1, %2" : "=v"(r) : "v"(lo), "v"(hi));
  return r;
}

__device__ __forceinline__ f32x4 mfma16(short8 a, short8 b, f32x4 c) {
  return __builtin_amdgcn_mfma_f32_16x16x32_bf16(a, b, c, 0, 0, 0);
}

__device__ __forceinline__ void gload_lds16(const u16* g, u16* l) {
  __builtin_amdgcn_global_load_lds(
      (const __attribute__((address_space(1))) unsigned int*)g,
      (__attribute__((address_space(3))) unsigned int*)l, 16, 0, 0);
}

// XCD-chunked bijective swizzle (nwg % 8 == 0 by construction here)
__device__ __forceinline__ int xcd_swz(int bid, int nwg) {
  int cpx = nwg >> 3;
  return (bid & 7) * cpx + (bid >> 3);
}

// NT loads: f32 sources are read-once (neutral-verified r14)
__device__ __forceinline__ void cvt8(const float* src, u16* dst) {
  f32x4 a = __builtin_nontemporal_load((const f32x4*)src);
  f32x4 b = __builtin_nontemporal_load((const f32x4*)(src + 4));
  uint4 u;
  u.x = cvtpk_bf16(a[0], a[1]);
  u.y = cvtpk_bf16(a[2], a[3]);
  u.z = cvtpk_bf16(b[0], b[1]);
  u.w = cvtpk_bf16(b[2], b[3]);
  *(uint4*)dst = u;
}

// ---------------- merged conversion: 4 weights + ent + feat, grid-stride --------
__global__ __launch_bounds__(256) void cvt_all_kernel(
    const float* __restrict__ w0, const float* __restrict__ w1,
    const float* __restrict__ w2, const float* __restrict__ w3,
    const float* __restrict__ ent, const float* __restrict__ feat,
    u16* __restrict__ Wbf, u16* __restrict__ entbf, u16* __restrict__ featbf,
    int nE8, int nF8) {
  const int nW8 = 524288;
  int total = nW8 + nE8 + nF8;
  int i = blockIdx.x * 256 + threadIdx.x;
  int stride = gridDim.x * 256;
  for (; i < total; i += stride) {
    if (i < nW8) {
      int mi = i >> 17;
      const float* s = (mi == 0) ? w0 : (mi == 1) ? w1 : (mi == 2) ? w2 : w3;
      size_t off = (size_t)(i & 131071) * 8;
      cvt8(s + off, Wbf + (size_t)mi * 1048576 + off);
    } else if (i < nW8 + nE8) {
      size_t off = (size_t)(i - nW8) * 8;
      cvt8(ent + off, entbf + off);
    } else {
      size_t off = (size_t)(i - nW8 - nE8) * 8;
      cvt8(feat + off, featbf + off);
    }
  }
}

__global__ __launch_bounds__(256) void cvt_a_kernel(
    const float* __restrict__ src, u16* __restrict__ dst, int n8) {
  int i = blockIdx.x * 256 + threadIdx.x;
  int stride = gridDim.x * 256;
  for (; i < n8; i += stride) cvt8(src + (size_t)i * 8, dst + (size_t)i * 8);
}

// ---------------- GEMM core: C[r,o]=sum A[r,:]W[o,:]+b  (HW-validated) ---------
template <bool OUT_F32>
__device__ __forceinline__ void gemm_core(
    const u16* __restrict__ A, const u16* __restrict__ B,
    const float* __restrict__ bias0, const float* __restrict__ bias1,
    void* __restrict__ Cv, int ldc, int bx, int by, u16* As, u16* Bs) {
  const int tid = threadIdx.x;
  const int lane = tid & 63;
  const int w = tid >> 6;
  const int wr = w >> 1, wc = w & 1;
  const int l15 = lane & 15, lg = lane >> 4;
  const int brow = by * 128;
  const int bcol = bx * 128;

  f32x4 acc[4][4] = {};

  for (int k0 = 0; k0 < 1024; k0 += 64) {
#pragma unroll
    for (int p = 0; p < 4; ++p) {
      int flat = p * 256 + tid;
      int row = flat >> 3;
      int scb = ((flat & 7) * 16) ^ SWZ(row);
      gload_lds16(B + (size_t)(bcol + row) * 1024 + k0 + (scb >> 1),
                  Bs + (size_t)flat * 8);
    }
#pragma unroll
    for (int p = 0; p < 4; ++p) {
      int flat = p * 256 + tid;
      int row = flat >> 3;
      int scb = ((flat & 7) * 16) ^ SWZ(row);
      gload_lds16(A + (size_t)(brow + row) * 1024 + k0 + (scb >> 1),
                  As + (size_t)flat * 8);
    }
    __syncthreads();

    short8 af[4][2], bfr[4][2];
#pragma unroll
    for (int i = 0; i < 4; ++i) {
#pragma unroll
      for (int kk = 0; kk < 2; ++kk) {
        int ar = wr * 64 + i * 16 + l15;
        af[i][kk] = *(const short8*)((const char*)As + ar * 128 +
                                     ((kk * 64 + lg * 16) ^ SWZ(ar)));
        int br = wc * 64 + i * 16 + l15;
        bfr[i][kk] = *(const short8*)((const char*)Bs + br * 128 +
                                      ((kk * 64 + lg * 16) ^ SWZ(br)));
      }
    }
#pragma unroll
    for (int i = 0; i < 4; ++i)
#pragma unroll
      for (int j = 0; j < 4; ++j)
#pragma unroll
        for (int kk = 0; kk < 2; ++kk)
          acc[i][j] = mfma16(af[i][kk], bfr[j][kk], acc[i][j]);
    __syncthreads();
  }

#pragma unroll
  for (int j = 0; j < 4; ++j) {
    int col = bcol + wc * 64 + j * 16 + l15;
    const float* bp = (col < 1024) ? bias0 : bias1;
    float bv = bp[col & 1023];
#pragma unroll
    for (int i = 0; i < 4; ++i) {
      int row0 = brow + wr * 64 + i * 16 + lg * 4;
#pragma unroll
      for (int r = 0; r < 4; ++r) {
        float v = acc[i][j][r] + bv;
        if constexpr (OUT_F32)
          ((float*)Cv)[(size_t)(row0 + r) * ldc + col] = v;
        else
          ((u16*)Cv)[(size_t)(row0 + r) * ldc + col] = f2bf(v);
      }
    }
  }
}

// ---------------- combined Q + KV projection per modality (932 TF proven) ------
__global__ __launch_bounds__(256, 2) void qkv_gemm_kernel(
    const u16* __restrict__ A0, const u16* __restrict__ B0,
    const float* __restrict__ bq, u16* __restrict__ C0, int gx0, int nwg0,
    const u16* __restrict__ A1, const u16* __restrict__ B1,
    const float* __restrict__ bk, const float* __restrict__ bv,
    u16* __restrict__ C1, int gx1, int nwg1) {
  __shared__ __attribute__((aligned(16))) u16 As[128 * 64];
  __shared__ __attribute__((aligned(16))) u16 Bs[128 * 64];
  int bid = blockIdx.x;
  if (bid < nwg0) {
    int lid = xcd_swz(bid, nwg0);
    gemm_core<false>(A0, B0, bq, bq, C0, 1024, lid % gx0, lid / gx0, As, Bs);
  } else {
    int lid = xcd_swz(bid - nwg0, nwg1);
    gemm_core<false>(A1, B1, bk, bv, C1, 2048, lid % gx1, lid / gx1, As, Bs);
  }
}

// ---------------- 2-segment Wo GEMM (f32 out; 512 blocks = full 2/CU) ----------
__global__ __launch_bounds__(256, 2) void wo2_kernel(
    const u16* __restrict__ A0, const u16* __restrict__ B0,
    const float* __restrict__ b0, float* __restrict__ C0, int n0,
    const u16* __restrict__ A1, const u16* __restrict__ B1,
    const float* __restrict__ b1, float* __restrict__ C1) {
  __shared__ __attribute__((aligned(16))) u16 As[128 * 64];
  __shared__ __attribute__((aligned(16))) u16 Bs[128 * 64];
  int bid = blockIdx.x;
  if (bid < n0) {
    int lid = xcd_swz(bid, n0);
    gemm_core<true>(A0, B0, b0, b0, C0, 1024, lid % 8, lid / 8, As, Bs);
  } else {
    int lid = xcd_swz(bid - n0, gridDim.x - n0);
    gemm_core<true>(A1, B1, b1, b1, C1, 1024, lid % 8, lid / 8, As, Bs);
  }
}

// ---------------- GEMM (legacy template for fallback paths) ----------
template <bool A_F32, bool OUT_F32>
__global__ __launch_bounds__(256, 2) void gemm_bias_kernel(
    const void* __restrict__ Av, const u16* __restrict__ B,
    const float* __restrict__ bias0, const float* __restrict__ bias1,
    void* __restrict__ Cv, int ldc) {
  __shared__ __attribute__((aligned(16))) u16 As[128 * 64];
  __shared__ __attribute__((aligned(16))) u16 Bs[128 * 64];
  const int tid = threadIdx.x;
  const int nwg = gridDim.x * gridDim.y;
  const int lid = xcd_swz(blockIdx.y * gridDim.x + blockIdx.x, nwg);
  const int bx = lid % gridDim.x;
  const int by = lid / gridDim.x;

  if constexpr (!A_F32) {
    gemm_core<OUT_F32>((const u16*)Av, B, bias0, bias1, Cv, ldc, bx, by, As, Bs);
    return;
  } else {
    const int lane = tid & 63;
    const int w = tid >> 6;
    const int wr = w >> 1, wc = w & 1;
    const int l15 = lane & 15, lg = lane >> 4;
    const int brow = by * 128;
    const int bcol = bx * 128;
    f32x4 acc[4][4] = {};
    for (int k0 = 0; k0 < 1024; k0 += 64) {
#pragma unroll
      for (int p = 0; p < 4; ++p) {
        int flat = p * 256 + tid;
        int row = flat >> 3;
        int scb = ((flat & 7) * 16) ^ SWZ(row);
        gload_lds16(B + (size_t)(bcol + row) * 1024 + k0 + (scb >> 1),
                    Bs + (size_t)flat * 8);
      }
      const float* Af = (const float*)Av;
#pragma unroll
      for (int p = 0; p < 4; ++p) {
        int flat = p * 256 + tid;
        int row = flat >> 3;
        int c8 = flat & 7;
        const float* src = Af + (size_t)(brow + row) * 1024 + k0 + c8 * 8;
        float4 v0 = ((const float4*)src)[0];
        float4 v1 = ((const float4*)src)[1];
        uint4 u;
        u.x = cvtpk_bf16(v0.x, v0.y);
        u.y = cvtpk_bf16(v0.z, v0.w);
        u.z = cvtpk_bf16(v1.x, v1.y);
        u.w = cvtpk_bf16(v1.z, v1.w);
        *(uint4*)((char*)As + row * 128 + ((c8 * 16) ^ SWZ(row))) = u;
      }
      __syncthreads();
      short8 af[4][2], bfr[4][2];
#pragma unroll
      for (int i = 0; i < 4; ++i) {
#pragma unroll
        for (int kk = 0; kk < 2; ++kk) {
          int ar = wr * 64 + i * 16 + l15;
          af[i][kk] = *(const short8*)((const char*)As + ar * 128 +
                                       ((kk * 64 + lg * 16) ^ SWZ(ar)));
          int br = wc * 64 + i * 16 + l15;
          bfr[i][kk] = *(const short8*)((const char*)Bs + br * 128 +
                                        ((kk * 64 + lg * 16) ^ SWZ(br)));
        }
      }
#pragma unroll
      for (int i = 0; i < 4; ++i)
#pragma unroll
        for (int j = 0; j < 4; ++j)
#pragma unroll
          for (int kk = 0; kk < 2; ++kk)
            acc[i][j] = mfma16(af[i][kk], bfr[j][kk], acc[i][j]);
      __syncthreads();
    }
#pragma unroll
    for (int j = 0; j < 4; ++j) {
      int col = bcol + wc * 64 + j * 16 + l15;
      const float* bp = (col < 1024) ? bias0 : bias1;
      float bv = bp[col & 1023];
#pragma unroll
      for (int i = 0; i < 4; ++i) {
        int row0 = brow + wr * 64 + i * 16 + lg * 4;
#pragma unroll
        for (int r = 0; r < 4; ++r) {
          float v = acc[i][j][r] + bv;
          if constexpr (OUT_F32)
            ((float*)Cv)[(size_t)(row0 + r) * ldc + col] = v;
          else
            ((u16*)Cv)[(size_t)(row0 + r) * ldc + col] = f2bf(v);
        }
      }
    }
  }
}

// ---------------- MFMA flash attention per (m_local, h) (r11 proven) -----------
__global__ __launch_bounds__(256, 2) void attn_mfma_kernel(
    const u16* __restrict__ Q, const u16* __restrict__ KV,
    const int* __restrict__ mask, u16* __restrict__ AO, int S, int mbase) {
  __shared__ __attribute__((aligned(16))) u16 Ks[64 * 64];
  __shared__ __attribute__((aligned(16))) u16 Vt[64 * 64];
  __shared__ __attribute__((aligned(16))) u16 Ps[4 * 32 * 64];
  __shared__ float mb[64];

  const int tid = threadIdx.x;
  const int lane = tid & 63;
  const int w = tid >> 6;
  const int lid = xcd_swz(blockIdx.x, gridDim.x);
  const int ml = lid >> 4;
  const int h = lid & 15;
  const int mg = mbase + ml;
  const int l15 = lane & 15, lg = lane >> 4;

  short8 qf[2][2];
#pragma unroll
  for (int qb = 0; qb < 2; ++qb)
#pragma unroll
    for (int kk = 0; kk < 2; ++kk)
      qf[qb][kk] = *(const short8*)(Q + (size_t)(mg * 128 + w * 32 + qb * 16 + l15) * 1024 +
                                    h * 64 + kk * 32 + lg * 8);

  float mrun[2][4], lrun[2][4];
  f32x4 oacc[2][4] = {};
#pragma unroll
  for (int qb = 0; qb < 2; ++qb)
#pragma unroll
    for (int r = 0; r < 4; ++r) {
      mrun[qb][r] = -1e30f;
      lrun[qb][r] = 0.0f;
    }

  const size_t kvbase = (size_t)ml * S * 2048 + h * 64;

  for (int st = 0; st < S; st += 64) {
    if (tid < 64)
      mb[tid] = (mask[(size_t)mg * S + st + tid] > 0) ? 0.0f : -1e30f;
#pragma unroll
    for (int p = 0; p < 2; ++p) {
      int flat = p * 256 + tid;
      int row = flat >> 3;
      int c = flat & 7;
      short8 v = *(const short8*)(KV + kvbase + (size_t)(st + row) * 2048 + c * 8);
      *(short8*)((char*)Ks + row * 128 + ((c * 16) ^ SWZ(row))) = v;
    }
    {
      int sp = (tid >> 3) * 2;
      int c = tid & 7;
      const u16* src = KV + kvbase + 1024 + (size_t)(st + sp) * 2048 + c * 8;
      short8 v0 = *(const short8*)(src);
      short8 v1 = *(const short8*)(src + 2048);
#pragma unroll
      for (int j = 0; j < 8; ++j) {
        int dr = c * 8 + j;
        unsigned int val = (unsigned int)(u16)v0[j] | ((unsigned int)(u16)v1[j] << 16);
        *(unsigned int*)((char*)Vt + dr * 128 + ((sp * 2) ^ SWZV(dr))) = val;
      }
    }
    __syncthreads();

    short8 kf[4][2];
#pragma unroll
    for (int sb = 0; sb < 4; ++sb)
#pragma unroll
      for (int kk = 0; kk < 2; ++kk) {
        int row = sb * 16 + l15;
        kf[sb][kk] = *(const short8*)((const char*)Ks + row * 128 +
                                      ((kk * 64 + lg * 16) ^ SWZ(row)));
      }
    f32x4 sc[2][4] = {};
#pragma unroll
    for (int qb = 0; qb < 2; ++qb)
#pragma unroll
      for (int sb = 0; sb < 4; ++sb)
#pragma unroll
        for (int kk = 0; kk < 2; ++kk)
          sc[qb][sb] = mfma16(qf[qb][kk], kf[sb][kk], sc[qb][sb]);

    float mbv[4];
#pragma unroll
    for (int sb = 0; sb < 4; ++sb) mbv[sb] = mb[sb * 16 + l15];

#pragma unroll
    for (int qb = 0; qb < 2; ++qb) {
#pragma unroll
      for (int r = 0; r < 4; ++r) {
        float s0 = sc[qb][0][r] * SCALE + mbv[0];
        float s1 = sc[qb][1][r] * SCALE + mbv[1];
        float s2 = sc[qb][2][r] * SCALE + mbv[2];
        float s3 = sc[qb][3][r] * SCALE + mbv[3];
        float t = fmaxf(fmaxf(s0, s1), fmaxf(s2, s3));
        for (int d = 1; d < 16; d <<= 1) t = fmaxf(t, __shfl_xor(t, d));
        float mnew = fmaxf(mrun[qb][r], t);
        float resc = __expf(mrun[qb][r] - mnew);
        float p0 = __expf(s0 - mnew);
        float p1 = __expf(s1 - mnew);
        float p2 = __expf(s2 - mnew);
        float p3 = __expf(s3 - mnew);
        float rs = p0 + p1 + p2 + p3;
        for (int d = 1; d < 16; d <<= 1) rs += __shfl_xor(rs, d);
        lrun[qb][r] = lrun[qb][r] * resc + rs;
        mrun[qb][r] = mnew;
#pragma unroll
        for (int db = 0; db < 4; ++db) oacc[qb][db][r] *= resc;
        int row = qb * 16 + lg * 4 + r;
        char* pbase = (char*)Ps + (w * 32 + row) * 128;
        int colb = 2 * l15;
        *(u16*)(pbase + ((0 * 32 + colb) ^ SWZ(row))) = f2bf(p0);
        *(u16*)(pbase + ((1 * 32 + colb) ^ SWZ(row))) = f2bf(p1);
        *(u16*)(pbase + ((2 * 32 + colb) ^ SWZ(row))) = f2bf(p2);
        *(u16*)(pbase + ((3 * 32 + colb) ^ SWZ(row))) = f2bf(p3);
      }
    }
    asm volatile("" ::: "memory");  // Ps wave-private: compiler fence only

    short8 pf[2][2], vf[4][2];
#pragma unroll
    for (int qb = 0; qb < 2; ++qb)
#pragma unroll
      for (int kk = 0; kk < 2; ++kk) {
        int row = qb * 16 + l15;
        pf[qb][kk] = *(const short8*)((const char*)Ps + (w * 32 + row) * 128 +
                                      ((kk * 64 + lg * 16) ^ SWZ(row)));
      }
#pragma unroll
    for (int db = 0; db < 4; ++db)
#pragma unroll
      for (int kk = 0; kk < 2; ++kk) {
        int row = db * 16 + l15;
        vf[db][kk] = *(const short8*)((const char*)Vt + row * 128 +
                                      ((kk * 64 + lg * 16) ^ SWZV(row)));
      }
#pragma unroll
    for (int qb = 0; qb < 2; ++qb)
#pragma unroll
      for (int db = 0; db < 4; ++db)
#pragma unroll
        for (int kk = 0; kk < 2; ++kk)
          oacc[qb][db] = mfma16(pf[qb][kk], vf[db][kk], oacc[qb][db]);
    __syncthreads();
  }

#pragma unroll
  for (int qb = 0; qb < 2; ++qb)
#pragma unroll
    for (int db = 0; db < 4; ++db)
#pragma unroll
      for (int r = 0; r < 4; ++r) {
        int grow = mg * 128 + w * 32 + qb * 16 + lg * 4 + r;
        int gcol = h * 64 + db * 16 + l15;
        float v = oacc[qb][db][r] / lrun[qb][r];
        AO[(size_t)grow * 1024 + gcol] = f2bf(v);
      }
}

// ---------------- residual + LayerNorm ----------------
__device__ __forceinline__ void ln_core(
    const float* __restrict__ X, const float* __restrict__ O,
    const float* __restrict__ g, const float* __restrict__ b,
    float* __restrict__ out, int row) {
  int tid = threadIdx.x;
  const float* xr = X + (size_t)row * 1024;
  const float* orr = O + (size_t)row * 1024;
  float4 xv = *(const float4*)(xr + tid * 4);
  float4 ov = *(const float4*)(orr + tid * 4);
  float v0 = xv.x + ov.x, v1 = xv.y + ov.y, v2 = xv.z + ov.z, v3 = xv.w + ov.w;
  float s = v0 + v1 + v2 + v3;
  float s2 = v0 * v0 + v1 * v1 + v2 * v2 + v3 * v3;
  for (int d = 1; d < 64; d <<= 1) {
    s += __shfl_xor(s, d);
    s2 += __shfl_xor(s2, d);
  }
  __shared__ float ps[4], ps2[4];
  int w = tid >> 6;
  if ((tid & 63) == 0) {
    ps[w] = s;
    ps2[w] = s2;
  }
  __syncthreads();
  s = ps[0] + ps[1] + ps[2] + ps[3];
  s2 = ps2[0] + ps2[1] + ps2[2] + ps2[3];
  float mu = s * (1.0f / 1024.0f);
  float var = s2 * (1.0f / 1024.0f) - mu * mu;
  float rstd = rsqrtf(var + 1e-5f);
  float4 gv = *(const float4*)(g + tid * 4);
  float4 bv = *(const float4*)(b + tid * 4);
  float4 ou;
  ou.x = (v0 - mu) * rstd * gv.x + bv.x;
  ou.y = (v1 - mu) * rstd * gv.y + bv.y;
  ou.z = (v2 - mu) * rstd * gv.z + bv.z;
  ou.w = (v3 - mu) * rstd * gv.w + bv.w;
  *(float4*)(out + (size_t)row * 1024 + tid * 4) = ou;
}

__global__ __launch_bounds__(256) void ln_kernel(
    const float* __restrict__ X, const float* __restrict__ O,
    const float* __restrict__ g, const float* __restrict__ b,
    float* __restrict__ out) {
  ln_core(X, O, g, b, out, blockIdx.x);
}

__global__ __launch_bounds__(256) void ln2_kernel(
    const float* __restrict__ X0, const float* __restrict__ O0,
    const float* __restrict__ g0, const float* __restrict__ b0,
    const float* __restrict__ X1, const float* __restrict__ O1,
    const float* __restrict__ g1, const float* __restrict__ b1,
    float* __restrict__ out) {
  int row = blockIdx.x;
  if (row < 4096)
    ln_core(X0, O0, g0, b0, out, row);
  else
    ln_core(X1, O1, g1, b1, out + 4194304, row - 4096);
}

extern "C" void kernel_launch(void* const* d_in, const int* in_sizes, int n_in,
                              void* d_out, int out_size, void* d_ws, size_t ws_size,
                              hipStream_t stream) {
  const float* ent_t = (const float*)d_in[0];
  const float* ent_i = (const float*)d_in[1];
  const float* img_feat = (const float*)d_in[2];
  const float* txt_feat = (const float*)d_in[3];
  const int* img_mask = (const int*)d_in[4];
  const int* txt_mask = (const int*)d_in[5];
  const float* W[8];
  const float* Bv[8];
  for (int i = 0; i < 8; ++i) {
    W[i] = (const float*)d_in[6 + 2 * i];
    Bv[i] = (const float*)d_in[7 + 2 * i];
  }
  const float* g_t = (const float*)d_in[22];
  const float* beta_t = (const float*)d_in[23];
  const float* g_i = (const float*)d_in[24];
  const float* beta_i = (const float*)d_in[25];
  float* out = (float*)d_out;
  char* ws = (char*)d_ws;

  if (ws_size >= (240ull << 20)) {
    // ===== r15 path (proven 493 µs): per-modality cvt→qkv→attn adjacency,
    //       deferred merged wo2 + ln2 tail-fill. 8 dispatches. =====
    // Wbf 16M (8 mats) | Qbf 8M | AObf_t 8M | AObf_i 8M | entbf 8M
    // | KVc 128M (Of32_t/Of32_i 32M alias) | featbf 64M   = 240M
    u16* Wbf = (u16*)ws;
    u16* Qbf = (u16*)(ws + (16ull << 20));
    u16* AObf_t = (u16*)(ws + (24ull << 20));
    u16* AObf_i = (u16*)(ws + (32ull << 20));
    u16* entbf = (u16*)(ws + (40ull << 20));
    u16* KVc = (u16*)(ws + (48ull << 20));
    u16* featbf = (u16*)(ws + (176ull << 20));
    float* Of32_t = (float*)(ws + (48ull << 20));            // alias KVc
    float* Of32_i = (float*)(ws + (48ull << 20) + (16ull << 20));

    for (int mod = 0; mod < 2; ++mod) {
      const float* ent = mod ? ent_i : ent_t;
      const float* feat = mod ? img_feat : txt_feat;
      const int* msk = mod ? img_mask : txt_mask;
      u16* AObf = mod ? AObf_i : AObf_t;
      int S = mod ? 768 : 1024;
      int crows = 32 * S;

      const u16* wq = Wbf + (size_t)mod * 4 * 1048576;
      const u16* wkv = Wbf + ((size_t)mod * 4 + 1) * 1048576;

      cvt_all_kernel<<<2048, 256, 0, stream>>>(
          W[mod * 4 + 0], W[mod * 4 + 1], W[mod * 4 + 2], W[mod * 4 + 3],
          ent, feat, Wbf + (size_t)mod * 4 * 1048576, entbf, featbf,
          4096 * 128, crows * 128);

      qkv_gemm_kernel<<<256 + 16 * (crows / 128), 256, 0, stream>>>(
          entbf, wq, Bv[mod * 4 + 0], Qbf, 8, 256,
          featbf, wkv, Bv[mod * 4 + 1], Bv[mod * 4 + 2], KVc, 16,
          16 * (crows / 128));

      attn_mfma_kernel<<<512, 256, 0, stream>>>(Qbf, KVc, msk, AObf, S, 0);
    }

    // merged epilogue: both Wo GEMMs fill 512 blocks (2/CU), then one LN
    wo2_kernel<<<512, 256, 0, stream>>>(
        AObf_t, Wbf + 3ull * 1048576, Bv[3], Of32_t, 256,
        AObf_i, Wbf + 7ull * 1048576, Bv[7], Of32_i);

    ln2_kernel<<<8192, 256, 0, stream>>>(
        ent_t, Of32_t, g_t, beta_t,
        ent_i, Of32_i, g_i, beta_i, out);
    return;
  }

  // ============ fallback: r11 proven path ============
  int nc = 0;
  size_t Xt = 0;
  for (int t = 1; t <= 4; t <<= 1) {
    size_t x = 134217728ull / t;
    if ((32ull << 20) + x + x / 2 <= ws_size) { nc = t; Xt = x; break; }
  }

  u16* Wbf = (u16*)ws;
  u16* Qbf = (u16*)(ws + (8ull << 20));
  u16* AObf = (u16*)(ws + (16ull << 20));

  if (nc > 0) {
    u16* entbf = (u16*)(ws + (24ull << 20));
    u16* KVc = (u16*)(ws + (32ull << 20));
    u16* featbf = (u16*)(ws + (32ull << 20) + Xt);
    float* Of32 = (float*)(ws + (32ull << 20));
    const int mpc = 32 / nc;

    for (int mod = 0; mod < 2; ++mod) {
      const float* ent = mod ? ent_i : ent_t;
      const float* feat = mod ? img_feat : txt_feat;
      const int* msk = mod ? img_mask : txt_mask;
      int S = mod ? 768 : 1024;
      int crows = mpc * S;

      const u16* wq = Wbf;
      const u16* wkv = Wbf + 1ull * 1048576;
      const u16* wo = Wbf + 3ull * 1048576;

      cvt_all_kernel<<<2048, 256, 0, stream>>>(
          W[mod * 4 + 0], W[mod * 4 + 1], W[mod * 4 + 2], W[mod * 4 + 3],
          ent, feat, Wbf, entbf, featbf, 4096 * 128, crows * 128);

      for (int c = 0; c < nc; ++c) {
        if (c > 0) {
          const float* featc = feat + (size_t)c * mpc * S * 1024;
          cvt_a_kernel<<<2048, 256, 0, stream>>>(featc, featbf, crows * 128);
        }
        int nwg0 = (c == 0) ? 256 : 0;
        int nwg1 = 16 * (crows / 128);
        qkv_gemm_kernel<<<nwg0 + nwg1, 256, 0, stream>>>(
            entbf, wq, Bv[mod * 4 + 0], Qbf, 8, nwg0,
            featbf, wkv, Bv[mod * 4 + 1], Bv[mod * 4 + 2], KVc, 16, nwg1);
        attn_mfma_kernel<<<mpc * 16, 256, 0, stream>>>(Qbf, KVc, msk, AObf, S, c * mpc);
      }

      gemm_bias_kernel<false, true><<<dim3(8, 32), 256, 0, stream>>>(
          AObf, wo, Bv[mod * 4 + 3], Bv[mod * 4 + 3], Of32, 1024);
      ln_kernel<<<4096, 256, 0, stream>>>(ent, Of32,
                                          mod ? g_i : g_t, mod ? beta_i : beta_t,
                                          out + (size_t)mod * 4194304);
    }
  } else {
    int ncf = 4;
    if (ws_size >= (152ull << 20)) ncf = 1;
    else if (ws_size >= (88ull << 20)) ncf = 2;
    u16* KVc = (u16*)(ws + (24ull << 20));
    float* Of32 = (float*)(ws + (24ull << 20));
    const int mpc = 32 / ncf;

    for (int mod = 0; mod < 2; ++mod) {
      const float* ent = mod ? ent_i : ent_t;
      const float* feat = mod ? img_feat : txt_feat;
      const int* msk = mod ? img_mask : txt_mask;
      int S = mod ? 768 : 1024;

      cvt_all_kernel<<<2048, 256, 0, stream>>>(
          W[mod * 4 + 0], W[mod * 4 + 1], W[mod * 4 + 2], W[mod * 4 + 3],
          ent, ent, Wbf, Qbf, Qbf, 0, 0);

      const u16* wq = Wbf;
      const u16* wkv = Wbf + 1ull * 1048576;
      const u16* wo = Wbf + 3ull * 1048576;

      gemm_bias_kernel<true, false><<<dim3(8, 32), 256, 0, stream>>>(
          ent, wq, Bv[mod * 4 + 0], Bv[mod * 4 + 0], Qbf, 1024);

      int crows = mpc * S;
      for (int c = 0; c < ncf; ++c) {
        const float* featc = feat + (size_t)c * mpc * S * 1024;
        gemm_bias_kernel<true, false><<<dim3(16, crows / 128), 256, 0, stream>>>(
            featc, wkv, Bv[mod * 4 + 1], Bv[mod * 4 + 2], KVc, 2048);
        attn_mfma_kernel<<<mpc * 16, 256, 0, stream>>>(Qbf, KVc, msk, AObf, S, c * mpc);
      }

      gemm_bias_kernel<false, true><<<dim3(8, 32), 256, 0, stream>>>(
          AObf, wo, Bv[mod * 4 + 3], Bv[mod * 4 + 3], Of32, 1024);
      ln_kernel<<<4096, 256, 0, stream>>>(ent, Of32,
                                          mod ? g_i : g_t, mod ? beta_i : beta_t,
                                          out + (size_t)mod * 4194304);
    }
  }
}